// Round 5
// baseline (567.879 us; speedup 1.0000x reference)
//
#include <hip/hip_runtime.h>
#include <hip/hip_bf16.h>

typedef __hip_bfloat16 bf16;
typedef __attribute__((ext_vector_type(8))) short bf16x8;
typedef __attribute__((ext_vector_type(4))) float f32x4;

constexpr int S_LEN  = 2048;
constexpr int D_DIM  = 512;
constexpr int KV_LEN = 2176;   // S + L
constexpr int L_LEN  = 128;
constexpr int POS_N  = 4223;   // S + KV - 1
constexpr int ATT_N  = 384;
constexpr int N_IN   = 52;

__device__ __forceinline__ float b2f(bf16 v){ return __bfloat162float(v); }
__device__ __forceinline__ bf16  f2b(float v){ return __float2bfloat16(v); }
__device__ __forceinline__ unsigned short f2bu(float v){
  bf16 h = __float2bfloat16(v);
  return *(unsigned short*)&h;
}

__device__ __forceinline__ float softplus_f(float x){
  return (x > 15.0f) ? x : __logf(1.0f + __expf(x));
}
__device__ __forceinline__ float swoosh_l_f(float x){
  return softplus_f(x - 4.0f) - 0.08f*x - 0.035f;
}
__device__ __forceinline__ float swoosh_r_f(float x){
  return softplus_f(x - 1.0f) - 0.08f*x - 0.313261687f;
}
__device__ __forceinline__ float tanh_fast(float x){
  const float xc = fminf(fmaxf(x, -15.f), 15.f);
  const float t = __expf(2.f*xc);
  return (t - 1.f) / (t + 1.f);
}

__device__ __forceinline__ void gload4(const float* p, float* d){
  const float4 v = *(const float4*)p;
  d[0]=v.x; d[1]=v.y; d[2]=v.z; d[3]=v.w;
}
__device__ __forceinline__ void gload4(const bf16* p, float* d){
  union { unsigned long long q; unsigned short u[4]; } w;
  w.q = *(const unsigned long long*)p;
  d[0] = __uint_as_float((unsigned)w.u[0] << 16);
  d[1] = __uint_as_float((unsigned)w.u[1] << 16);
  d[2] = __uint_as_float((unsigned)w.u[2] << 16);
  d[3] = __uint_as_float((unsigned)w.u[3] << 16);
}

// ============ dtype detect + ingest ============
__global__ void detect_kernel(const unsigned short* __restrict__ src_u16, int* __restrict__ flag){
  int wild = 0;
  for (int i = threadIdx.x; i < 1024; i += 64) {
    float v = __uint_as_float((unsigned)src_u16[i] << 16);
    if (!(fabsf(v) <= 1e10f)) wild++;
  }
  #pragma unroll
  for (int off=32; off; off>>=1) wild += __shfl_down(wild, off);
  if (threadIdx.x == 0) *flag = (wild > 16) ? 1 : 0;
}

struct Ptrs { const void* p[N_IN]; };
struct Segs { int start[N_IN]; int elems[N_IN]; int kind[N_IN]; int dstoff[N_IN]; int rows[N_IN]; };
// kind: 0 = to canonical bf16; 1 = src -> fp32 srcf + bf16 srcb; 2 = skip;
//       3 = transpose [rows x cols] -> bf16 [cols x rows] at dstoff (LDS-tiled, 32x32).

__global__ void ingest_kernel(Ptrs ptrs, Segs segs, const int* __restrict__ flag,
                              bf16* __restrict__ canon, float* __restrict__ srcf,
                              bf16* __restrict__ srcb){
  const int f = *flag;   // 1 = fp32 source, 0 = bf16 source (uniform branch)
  const int b = blockIdx.x;
  const int tid = threadIdx.x;
  int t = 0;
  #pragma unroll 1
  for (int i = 1; i < N_IN; i++) if (b >= segs.start[i]) t = i;
  const int kind = segs.kind[t];
  if (kind == 2) return;
  const int n = segs.elems[t];
  const void* sp = ptrs.p[t];

  if (kind == 3) {
    __shared__ float tile[32][33];
    const int R = segs.rows[t];
    const int C = n / R;
    const int ctiles = C >> 5;
    const int tb = b - segs.start[t];
    const int ri = tb / ctiles, ci = tb - ri*ctiles;
    const int r0 = ri << 5, c0 = ci << 5;
    const int row = tid >> 3, cg = tid & 7;
    float v[4];
    if (f) gload4((const float*)sp + (size_t)(r0+row)*C + c0 + cg*4, v);
    else   gload4((const bf16*)sp  + (size_t)(r0+row)*C + c0 + cg*4, v);
    tile[cg*4+0][row] = v[0]; tile[cg*4+1][row] = v[1];
    tile[cg*4+2][row] = v[2]; tile[cg*4+3][row] = v[3];
    __syncthreads();
    ushort4 o;
    o.x = f2bu(tile[row][cg*4+0]); o.y = f2bu(tile[row][cg*4+1]);
    o.z = f2bu(tile[row][cg*4+2]); o.w = f2bu(tile[row][cg*4+3]);
    *(ushort4*)&canon[segs.dstoff[t] + (size_t)(c0+row)*R + r0 + cg*4] = o;
    return;
  }

  const int base = (b - segs.start[t]) * 1024 + tid * 4;
  #pragma unroll
  for (int k = 0; k < 4; k++) {
    const int e = base + k;
    if (e >= n) break;
    float v;
    if (f) v = ((const float*)sp)[e];
    else   v = b2f(((const bf16*)sp)[e]);
    if (kind == 1) { srcf[e] = v; srcb[e] = f2b(v); }
    else canon[segs.dstoff[t] + e] = f2b(v);
  }
}

__global__ void zero_kernel(float* __restrict__ p, int n){
  int i = blockIdx.x*256 + threadIdx.x;
  if (i < n) p[i] = 0.f;
}

// ---- MFMA GEMM 64x64 tile, BK=64, dbuf LDS, prefetch-2 global loads ----
// dbuf race-freedom: read(buf p, iter i) precedes barrier(i+1); write(buf p,
// iter i+2) follows barrier(i+1). prefetch-2: tile k+2 issued in iter k,
// consumed (LDS store) at top of iter k+2 -> ~2 iterations of latency cover.
template<int ACT>
__global__ __launch_bounds__(256) void mfma_gemm64b(
    const bf16* __restrict__ A, const bf16* __restrict__ Bt,
    const bf16* __restrict__ bias, const float* __restrict__ residual,
    float* __restrict__ Cf, bf16* __restrict__ Cb, int M, int N, int K)
{
  __shared__ __align__(16) short As[2][64*72];
  __shared__ __align__(16) short Bs[2][64*72];
  const int tid = threadIdx.x;
  const int wave = tid >> 6, lane = tid & 63;
  const int l15 = lane & 15, quad = lane >> 4;
  const int m0 = blockIdx.y*64, n0 = blockIdx.x*64;

  f32x4 acc[4];
  #pragma unroll
  for (int nt=0;nt<4;nt++) acc[nt] = (f32x4){0.f,0.f,0.f,0.f};

  const int arow = tid >> 2, aoff = (tid & 3) * 16;
  const bf16* aptr = A + (size_t)(m0 + arow)*K + aoff;
  const bf16* bptr = (n0 + arow < N) ? (Bt + (size_t)(n0 + arow)*K + aoff) : nullptr;

  uint4 pa0 = *(const uint4*)(aptr);
  uint4 pa1 = *(const uint4*)(aptr + 8);
  uint4 pb0 = make_uint4(0u,0u,0u,0u), pb1 = make_uint4(0u,0u,0u,0u);
  if (bptr) { pb0 = *(const uint4*)(bptr); pb1 = *(const uint4*)(bptr + 8); }
  uint4 qa0 = pa0, qa1 = pa1, qb0 = pb0, qb1 = pb1;
  if (K > 64) {
    qa0 = *(const uint4*)(aptr + 64);
    qa1 = *(const uint4*)(aptr + 72);
    if (bptr) { qb0 = *(const uint4*)(bptr + 64); qb1 = *(const uint4*)(bptr + 72); }
  }

  int p = 0;
  for (int k0 = 0; k0 < K; k0 += 64) {
    *(uint4*)&As[p][arow*72 + aoff]     = pa0;
    *(uint4*)&As[p][arow*72 + aoff + 8] = pa1;
    *(uint4*)&Bs[p][arow*72 + aoff]     = pb0;
    *(uint4*)&Bs[p][arow*72 + aoff + 8] = pb1;
    __syncthreads();
    pa0 = qa0; pa1 = qa1; pb0 = qb0; pb1 = qb1;
    if (k0 + 128 < K) {
      qa0 = *(const uint4*)(aptr + k0 + 128);
      qa1 = *(const uint4*)(aptr + k0 + 136);
      if (bptr) { qb0 = *(const uint4*)(bptr + k0 + 128); qb1 = *(const uint4*)(bptr + k0 + 136); }
    }
    bf16x8 af0 = *(const bf16x8*)&As[p][(wave*16 + l15)*72 +      quad*8];
    bf16x8 af1 = *(const bf16x8*)&As[p][(wave*16 + l15)*72 + 32 + quad*8];
    #pragma unroll
    for (int nt=0;nt<4;nt++){
      bf16x8 b0 = *(const bf16x8*)&Bs[p][(nt*16 + l15)*72 +      quad*8];
      bf16x8 b1 = *(const bf16x8*)&Bs[p][(nt*16 + l15)*72 + 32 + quad*8];
      acc[nt] = __builtin_amdgcn_mfma_f32_16x16x32_bf16(af0, b0, acc[nt], 0,0,0);
      acc[nt] = __builtin_amdgcn_mfma_f32_16x16x32_bf16(af1, b1, acc[nt], 0,0,0);
    }
    p ^= 1;
  }

  #pragma unroll
  for (int nt=0;nt<4;nt++){
    const int col = n0 + nt*16 + l15;
    if (col >= N) continue;
    const float bb = bias ? b2f(bias[col]) : 0.f;
    #pragma unroll
    for (int r=0;r<4;r++){
      const int row = m0 + wave*16 + quad*4 + r;
      float v = acc[nt][r] + bb;
      if (ACT == 1) v = swoosh_l_f(v);
      const size_t ci = (size_t)row*N + col;
      if (residual) v += residual[ci];
      if (Cf) Cf[ci] = v;
      if (Cb) Cb[ci] = f2b(v);
    }
  }
}

// ---- MFMA GEMM 64x64 tile, BK=32 (for K not divisible by 64) ----
template<int ACT>
__global__ __launch_bounds__(256) void mfma_gemm64(
    const bf16* __restrict__ A, const bf16* __restrict__ Bt,
    const bf16* __restrict__ bias, const float* __restrict__ residual,
    float* __restrict__ Cf, bf16* __restrict__ Cb, int M, int N, int K)
{
  __shared__ __align__(16) short As[2][64*40];
  __shared__ __align__(16) short Bs[2][64*40];
  const int tid = threadIdx.x;
  const int wave = tid >> 6, lane = tid & 63;
  const int l15 = lane & 15, quad = lane >> 4;
  const int m0 = blockIdx.y*64, n0 = blockIdx.x*64;

  f32x4 acc[4];
  #pragma unroll
  for (int nt=0;nt<4;nt++) acc[nt] = (f32x4){0.f,0.f,0.f,0.f};

  const int arow = tid >> 2, aoff = (tid & 3) * 8;
  const bf16* aptr = A + (size_t)(m0 + arow)*K + aoff;
  const bf16* bptr = (n0 + arow < N) ? (Bt + (size_t)(n0 + arow)*K + aoff) : nullptr;

  uint4 av = *(const uint4*)(aptr);
  uint4 bv = make_uint4(0u,0u,0u,0u);
  if (bptr) bv = *(const uint4*)(bptr);

  int p = 0;
  for (int k0 = 0; k0 < K; k0 += 32) {
    *(uint4*)&As[p][arow*40 + aoff] = av;
    *(uint4*)&Bs[p][arow*40 + aoff] = bv;
    __syncthreads();
    if (k0 + 32 < K) {
      av = *(const uint4*)(aptr + k0 + 32);
      if (bptr) bv = *(const uint4*)(bptr + k0 + 32);
    }
    bf16x8 af = *(const bf16x8*)&As[p][(wave*16 + l15)*40 + quad*8];
    #pragma unroll
    for (int nt=0;nt<4;nt++){
      bf16x8 bfr = *(const bf16x8*)&Bs[p][(nt*16 + l15)*40 + quad*8];
      acc[nt] = __builtin_amdgcn_mfma_f32_16x16x32_bf16(af, bfr, acc[nt], 0,0,0);
    }
    p ^= 1;
  }

  #pragma unroll
  for (int nt=0;nt<4;nt++){
    const int col = n0 + nt*16 + l15;
    if (col >= N) continue;
    const float bb = bias ? b2f(bias[col]) : 0.f;
    #pragma unroll
    for (int r=0;r<4;r++){
      const int row = m0 + wave*16 + quad*4 + r;
      float v = acc[nt][r] + bb;
      if (ACT == 1) v = swoosh_l_f(v);
      const size_t ci = (size_t)row*N + col;
      if (residual) v += residual[ci];
      if (Cf) Cf[ci] = v;
      if (Cb) Cb[ci] = f2b(v);
    }
  }
}

// ---- K-chunked GEMM, BK=64, prefetch-2: plain stores into per-z slices ----
__global__ __launch_bounds__(256) void gemm_chunk64(
    const bf16* __restrict__ A, const bf16* __restrict__ Bt,
    float* __restrict__ C, int N, int K, int kLen)
{
  __shared__ __align__(16) short As[2][64*72];
  __shared__ __align__(16) short Bs[2][64*72];
  const int tid = threadIdx.x;
  const int wave = tid >> 6, lane = tid & 63;
  const int l15 = lane & 15, quad = lane >> 4;
  const int n0 = blockIdx.x*64, m0 = blockIdx.y*64;
  const int kBeg = blockIdx.z * kLen;

  f32x4 acc[4];
  #pragma unroll
  for (int nt=0;nt<4;nt++) acc[nt] = (f32x4){0.f,0.f,0.f,0.f};

  const int arow = tid >> 2, aoff = (tid & 3) * 16;
  const bf16* aptr = A + (size_t)(m0 + arow)*K + kBeg + aoff;
  const bf16* bptr = Bt + (size_t)(n0 + arow)*K + kBeg + aoff;

  uint4 pa0 = *(const uint4*)(aptr);
  uint4 pa1 = *(const uint4*)(aptr + 8);
  uint4 pb0 = *(const uint4*)(bptr);
  uint4 pb1 = *(const uint4*)(bptr + 8);
  uint4 qa0 = pa0, qa1 = pa1, qb0 = pb0, qb1 = pb1;
  if (kLen > 64) {
    qa0 = *(const uint4*)(aptr + 64);
    qa1 = *(const uint4*)(aptr + 72);
    qb0 = *(const uint4*)(bptr + 64);
    qb1 = *(const uint4*)(bptr + 72);
  }

  int p = 0;
  for (int k0 = 0; k0 < kLen; k0 += 64) {
    *(uint4*)&As[p][arow*72 + aoff]     = pa0;
    *(uint4*)&As[p][arow*72 + aoff + 8] = pa1;
    *(uint4*)&Bs[p][arow*72 + aoff]     = pb0;
    *(uint4*)&Bs[p][arow*72 + aoff + 8] = pb1;
    __syncthreads();
    pa0 = qa0; pa1 = qa1; pb0 = qb0; pb1 = qb1;
    if (k0 + 128 < kLen) {
      qa0 = *(const uint4*)(aptr + k0 + 128);
      qa1 = *(const uint4*)(aptr + k0 + 136);
      qb0 = *(const uint4*)(bptr + k0 + 128);
      qb1 = *(const uint4*)(bptr + k0 + 136);
    }
    bf16x8 af0 = *(const bf16x8*)&As[p][(wave*16 + l15)*72 +      quad*8];
    bf16x8 af1 = *(const bf16x8*)&As[p][(wave*16 + l15)*72 + 32 + quad*8];
    #pragma unroll
    for (int nt=0;nt<4;nt++){
      bf16x8 b0 = *(const bf16x8*)&Bs[p][(nt*16 + l15)*72 +      quad*8];
      bf16x8 b1 = *(const bf16x8*)&Bs[p][(nt*16 + l15)*72 + 32 + quad*8];
      acc[nt] = __builtin_amdgcn_mfma_f32_16x16x32_bf16(af0, b0, acc[nt], 0,0,0);
      acc[nt] = __builtin_amdgcn_mfma_f32_16x16x32_bf16(af1, b1, acc[nt], 0,0,0);
    }
    p ^= 1;
  }

  float* Cz = C + (size_t)blockIdx.z * (size_t)S_LEN * N;
  #pragma unroll
  for (int nt=0;nt<4;nt++){
    const int col = n0 + nt*16 + l15;
    #pragma unroll
    for (int r=0;r<4;r++){
      const int row = m0 + wave*16 + quad*4 + r;
      Cz[(size_t)row*N + col] = acc[nt][r];
    }
  }
}

// ---- down-proj epilogue: sum 2 K-chunks + bias + residual (+ optional mid-bypass) ----
__global__ void down_epi_kernel(const float* __restrict__ gacc, int chunks,
                                const bf16* __restrict__ bias, const float* __restrict__ res,
                                const float* __restrict__ srcf, const bf16* __restrict__ bms,
                                float* __restrict__ outf, bf16* __restrict__ outb){
  int idx = blockIdx.x*256 + threadIdx.x;
  if (idx >= S_LEN*D_DIM) return;
  float v = gacc[idx];
  #pragma unroll 1
  for (int z=1; z<chunks; z++) v += gacc[idx + (size_t)z*S_LEN*D_DIM];
  v += b2f(bias[idx & 511]) + res[idx];
  if (bms) {
    const float o = srcf[idx];
    v = o + (v - o)*b2f(bms[idx & 511]);
  }
  outf[idx] = v;
  outb[idx] = f2b(v);
}

// ---- nonlin-attn epilogue: sum 2 K-chunks, gate, normalize ----
__global__ void na_epi_kernel(const float* __restrict__ part, const float* __restrict__ xna,
                              const float* __restrict__ l0, bf16* __restrict__ t1b){
  int idx = blockIdx.x*256 + threadIdx.x;
  if (idx >= S_LEN*ATT_N) return;
  const int SL = S_LEN*ATT_N;
  float v = part[idx] + part[idx+SL];
  int s = idx / ATT_N, c = idx - s*ATT_N;
  t1b[idx] = f2b(v * xna[(size_t)s*1152 + 768 + c] / l0[s]);
}

// ---- attention apply: barrier-free, LDS-free, direct-to-register MFMA ----
__global__ __launch_bounds__(256) void apply_gemm(
    const bf16* __restrict__ attnw, const bf16* __restrict__ vcT,
    const float* __restrict__ l, bf16* __restrict__ o)
{
  const int h = blockIdx.y;
  const int m0 = blockIdx.x*64;
  const int tid = threadIdx.x;
  const int wave = tid >> 6, lane = tid & 63;
  const int l15 = lane & 15, quad = lane >> 4;
  const int vr = (l15 < 12) ? l15 : 11;   // clamp unused B cols in-bounds

  const bf16* aptr = attnw + ((size_t)h*S_LEN + m0 + wave*16 + l15)*KV_LEN + quad*8;
  const bf16* bptr = vcT   + ((size_t)h*12 + vr)*KV_LEN + quad*8;

  f32x4 acc = (f32x4){0.f,0.f,0.f,0.f};
  #pragma unroll 1
  for (int k0 = 0; k0 < KV_LEN; k0 += 128) {   // 17 groups of 4 MFMA
    bf16x8 a0 = *(const bf16x8*)(aptr + k0);
    bf16x8 a1 = *(const bf16x8*)(aptr + k0 + 32);
    bf16x8 a2 = *(const bf16x8*)(aptr + k0 + 64);
    bf16x8 a3 = *(const bf16x8*)(aptr + k0 + 96);
    bf16x8 b0 = *(const bf16x8*)(bptr + k0);
    bf16x8 b1 = *(const bf16x8*)(bptr + k0 + 32);
    bf16x8 b2 = *(const bf16x8*)(bptr + k0 + 64);
    bf16x8 b3 = *(const bf16x8*)(bptr + k0 + 96);
    acc = __builtin_amdgcn_mfma_f32_16x16x32_bf16(a0, b0, acc, 0,0,0);
    acc = __builtin_amdgcn_mfma_f32_16x16x32_bf16(a1, b1, acc, 0,0,0);
    acc = __builtin_amdgcn_mfma_f32_16x16x32_bf16(a2, b2, acc, 0,0,0);
    acc = __builtin_amdgcn_mfma_f32_16x16x32_bf16(a3, b3, acc, 0,0,0);
  }

  if (l15 < 12) {
    #pragma unroll
    for (int r=0;r<4;r++){
      const int row = m0 + wave*16 + quad*4 + r;
      o[(size_t)row*96 + h*12 + l15] = f2b(acc[r] / l[(size_t)h*S_LEN + row]);
    }
  }
}

__global__ void pe_kernel(const bf16* __restrict__ pos_emb, const bf16* __restrict__ pos_w,
                          float* __restrict__ pe){
  int idx = blockIdx.x*256 + threadIdx.x;
  if (idx >= POS_N*32) return;
  int p = idx >> 5, j = idx & 31;
  float acc = 0.f;
  #pragma unroll 8
  for (int d=0; d<48; d++) acc += b2f(pos_emb[p*48+d]) * b2f(pos_w[d*32+j]);
  pe[idx] = acc;
}

__global__ void newkey_kernel(const float* __restrict__ xattn, float* __restrict__ out){
  int idx = blockIdx.x*256 + threadIdx.x;
  if (idx >= 128*256) return;
  int r = idx >> 8, c = idx & 255;
  out[idx] = xattn[(size_t)(1912+r)*544 + 256 + c];
}

// ======== single-pass attention weights, QK^T on MFMA, coalesced stores ========
__global__ __launch_bounds__(256) void attn_exp_mfma(
    const bf16* __restrict__ xattnb, const float* __restrict__ xattn,
    const bf16* __restrict__ cached_key, const float* __restrict__ pe,
    float* __restrict__ l, bf16* __restrict__ attnw)
{
  const int h = blockIdx.z;
  const int t0 = blockIdx.x * 64;
  const int s0 = blockIdx.y * 64;
  __shared__ __align__(16) short QK[2*64*40];   // Qs | Ks ; reused for score staging
  short* Qs = QK;
  short* Ks = QK + 64*40;
  __shared__ __align__(16) float4 Psf[64];
  __shared__ __align__(16) float4 Pwf[127*5];
  const int tid = threadIdx.x;
  const int wave = tid >> 6, lane = tid & 63;
  const int l15 = lane & 15, quad = lane >> 4;

  {
    const int r = tid >> 2, cg = tid & 3;
    *(uint4*)&Qs[r*40 + cg*8] =
      *(const uint4*)(xattnb + (size_t)(s0+r)*544 + h*32 + cg*8);
  }
  {
    const int r = tid >> 2, cg = tid & 3;
    uint4 kv;
    if (t0 < L_LEN) kv = *(const uint4*)(cached_key + (size_t)(t0+r)*256 + h*32 + cg*8);
    else            kv = *(const uint4*)(xattnb + (size_t)(t0+r-L_LEN)*544 + 256 + h*32 + cg*8);
    *(uint4*)&Ks[r*40 + cg*8] = kv;
  }
  if (tid < 64) Psf[tid] = *(const float4*)(xattn + (size_t)(s0+tid)*544 + 512 + h*4);
  const int pbase = s0 - t0 + KV_LEN - 1 - 63;
  if (tid < 127) Pwf[tid*5] = *(const float4*)(pe + (size_t)(pbase+tid)*32 + h*4);
  __syncthreads();

  bf16x8 af = *(const bf16x8*)&Qs[(wave*16 + l15)*40 + quad*8];
  bf16x8 bfr[4];
  #pragma unroll
  for (int nt=0;nt<4;nt++) bfr[nt] = *(const bf16x8*)&Ks[(nt*16 + l15)*40 + quad*8];
  f32x4 acc[4];
  #pragma unroll
  for (int nt=0;nt<4;nt++)
    acc[nt] = __builtin_amdgcn_mfma_f32_16x16x32_bf16(af, bfr[nt], (f32x4){0.f,0.f,0.f,0.f}, 0,0,0);

  // epilogue compute: scores -> exp, keep in regs, row sums
  float rowsum[4] = {0.f,0.f,0.f,0.f};
  unsigned short ev[4][4];
  #pragma unroll
  for (int nt=0;nt<4;nt++){
    const int tl = nt*16 + l15;
    #pragma unroll
    for (int r=0;r<4;r++){
      const int sl = wave*16 + quad*4 + r;
      const float4 pv = Psf[sl];
      const float4 pp = Pwf[(sl - tl + 63)*5];
      const float sc = acc[nt][r]*0.17677669529663687f
                     + pv.x*pp.x + pv.y*pp.y + pv.z*pp.z + pv.w*pp.w;
      const float e = __expf(sc - 12.0f);
      rowsum[r] += e;
      ev[nt][r] = f2bu(e);
    }
  }
  #pragma unroll
  for (int r=0;r<4;r++){
    float rs = rowsum[r];
    #pragma unroll
    for (int msk = 1; msk < 16; msk <<= 1) rs += __shfl_xor(rs, msk);
    if (l15 == 0) {
      const int sg = s0 + wave*16 + quad*4 + r;
      atomicAdd(&l[(size_t)h*S_LEN + sg], rs);
    }
  }

  // stage score tile in LDS (reuse QK region), then coalesced 16B stores
  __syncthreads();
  unsigned short* Sc = (unsigned short*)QK;   // 64 rows x 72 stride (144B, 16B-aligned)
  #pragma unroll
  for (int nt=0;nt<4;nt++){
    const int tl = nt*16 + l15;
    #pragma unroll
    for (int r=0;r<4;r++){
      Sc[(wave*16 + quad*4 + r)*72 + tl] = ev[nt][r];
    }
  }
  __syncthreads();
  const int sr = tid >> 2, cg = tid & 3;
  const uint4 w0 = *(const uint4*)&Sc[sr*72 + cg*16];
  const uint4 w1 = *(const uint4*)&Sc[sr*72 + cg*16 + 8];
  bf16* orow = attnw + ((size_t)h*S_LEN + s0 + sr)*KV_LEN + t0 + cg*16;
  *(uint4*)orow = w0;
  *(uint4*)(orow + 8) = w1;
}

// ---- nonlin-attn mid: LDS-tiled transpose, 32x32 per block ----
// grid (68 t-tiles, 12 c-tiles)
__global__ __launch_bounds__(256) void na_mid_kernel(
    const float* __restrict__ xna, const bf16* __restrict__ cached,
    bf16* __restrict__ xcT, float* __restrict__ out_nl)
{
  __shared__ float tile[32][33];
  const int t0 = blockIdx.x*32, c0 = blockIdx.y*32;
  const int tid = threadIdx.x;
  const int row = tid >> 3, cg = tid & 7;
  const int t = t0 + row;
  float v[4];
  if (t < L_LEN) {
    gload4(cached + (size_t)t*ATT_N + c0 + cg*4, v);
  } else {
    const int s = t - L_LEN;
    const float4 sv = *(const float4*)(xna + (size_t)s*1152 + c0 + cg*4);
    const float4 xv = *(const float4*)(xna + (size_t)s*1152 + 384 + c0 + cg*4);
    v[0] = xv.x * tanh_fast(sv.x); v[1] = xv.y * tanh_fast(sv.y);
    v[2] = xv.z * tanh_fast(sv.z); v[3] = xv.w * tanh_fast(sv.w);
    if (t >= 2040 && t < 2168)
      *(float4*)(out_nl + (size_t)(t-2040)*ATT_N + c0 + cg*4) = make_float4(v[0],v[1],v[2],v[3]);
  }
  tile[cg*4+0][row] = v[0]; tile[cg*4+1][row] = v[1];
  tile[cg*4+2][row] = v[2]; tile[cg*4+3][row] = v[3];
  __syncthreads();
  ushort4 o;
  o.x = f2bu(tile[row][cg*4+0]); o.y = f2bu(tile[row][cg*4+1]);
  o.z = f2bu(tile[row][cg*4+2]); o.w = f2bu(tile[row][cg*4+3]);
  *(ushort4*)&xcT[(size_t)(c0+row)*KV_LEN + t0 + cg*4] = o;
}

__global__ void vc_build_kernel(const float* __restrict__ v96, const bf16* __restrict__ cached,
                                bf16* __restrict__ vcT, float* __restrict__ out_v){
  int idx = blockIdx.x*256 + threadIdx.x;
  if (idx >= KV_LEN*96) return;
  int c = idx / KV_LEN, t = idx - c*KV_LEN;
  float v;
  if (t < L_LEN) { vcT[idx] = cached[t*96 + c]; return; }
  v = v96[(size_t)(t-L_LEN)*96 + c];
  vcT[idx] = f2b(v);
  if (t >= 2040 && t < 2168) out_v[(t-2040)*96 + c] = v;
}

// ---- conv GLU: LDS-tiled transpose into uT (stride 2080, data at offset 32) ----
// grid (64 s-tiles, 16 c-tiles)
__global__ __launch_bounds__(256) void conv_glu_kernel(
    const float* __restrict__ xcv, float* __restrict__ uT, float* __restrict__ out_c)
{
  __shared__ float tile[32][33];
  const int s0 = blockIdx.x*32, c0 = blockIdx.y*32;
  const int tid = threadIdx.x;
  const int row = tid >> 3, cg = tid & 7;
  const int s = s0 + row;
  const float* base = xcv + (size_t)s*1024 + c0 + cg*4;
  const float4 a = *(const float4*)base;
  const float4 g = *(const float4*)(base + 512);
  float v[4];
  v[0] = a.x / (1.0f + __expf(-g.x)); v[1] = a.y / (1.0f + __expf(-g.y));
  v[2] = a.z / (1.0f + __expf(-g.z)); v[3] = a.w / (1.0f + __expf(-g.w));
  if (s >= 2010 && s < 2040) {
    #pragma unroll
    for (int j=0;j<4;j++) out_c[(c0+cg*4+j)*30 + (s-2010)] = v[j];
  }
  tile[cg*4+0][row] = v[0]; tile[cg*4+1][row] = v[1];
  tile[cg*4+2][row] = v[2]; tile[cg*4+3][row] = v[3];
  __syncthreads();
  const float4 w = make_float4(tile[row][cg*4+0], tile[row][cg*4+1],
                               tile[row][cg*4+2], tile[row][cg*4+3]);
  *(float4*)&uT[(size_t)(c0+row)*2080 + 32 + s0 + cg*4] = w;
}

// ---- depthwise conv; first s-block reads the conv cache directly ----
__global__ __launch_bounds__(256) void dwconv_kernel(const float* __restrict__ uT,
    const bf16* __restrict__ cached,
    const bf16* __restrict__ dww, const bf16* __restrict__ dwb, bf16* __restrict__ y){
  const int c = blockIdx.y, s0 = blockIdx.x * 256, tid = threadIdx.x;
  __shared__ float w[32];
  __shared__ float xb[256+31];
  if (tid < 31) w[tid] = b2f(dww[c*31 + tid]);
  for (int i = tid; i < 286; i += 256) {
    float val;
    if (s0 == 0 && i < 30) val = b2f(cached[c*30 + i]);
    else                   val = uT[(size_t)c*2080 + 2 + s0 + i];
    xb[i] = val;
  }
  __syncthreads();
  float acc = b2f(dwb[c]);
  #pragma unroll
  for (int j=0;j<31;j++) acc += xb[tid+j]*w[j];
  y[(size_t)(s0+tid)*512 + c] = f2b(swoosh_r_f(acc));
}

__global__ __launch_bounds__(256) void final_kernel(const float* __restrict__ cur,
    const float* __restrict__ srcf, const bf16* __restrict__ nbias,
    const bf16* __restrict__ nls, const bf16* __restrict__ bys, float* __restrict__ out){
  const int s = blockIdx.x, tid = threadIdx.x;
  __shared__ float red[4];
  float p = 0.f;
  for (int c=tid; c<512; c+=256){
    float d = cur[(size_t)s*512+c] - b2f(nbias[c]);
    p += d*d;
  }
  #pragma unroll
  for (int off=32; off; off>>=1) p += __shfl_down(p, off);
  if ((tid & 63) == 0) red[tid>>6] = p;
  __syncthreads();
  const float ms = (red[0]+red[1]+red[2]+red[3]) * (1.0f/512.0f);
  const float scale = expf(b2f(nls[0])) / sqrtf(ms);
  for (int c=tid; c<512; c+=256){
    float v = cur[(size_t)s*512+c]*scale;
    float o = srcf[(size_t)s*512+c];
    out[(size_t)s*512+c] = o + (v-o)*b2f(bys[c]);
  }
}

// =====================================================================
extern "C" void kernel_launch(void* const* d_in, const int* in_sizes, int n_in,
                              void* d_out, int out_size, void* d_ws, size_t ws_size,
                              hipStream_t stream) {
  if (n_in < N_IN) return;

  auto trows = [](int i)->int{
    switch (i) {
      case 14: return 1536; case 18: return 2048; case 22: return 2560;
      case 26: return 384;  case 30: return 96;   case 34: return 96;
      case 9: case 12: case 16: case 20: case 24: case 28: case 32:
      case 36: case 40: case 42: case 46: return 512;
      default: return 0;
    }
  };

  Ptrs ptrs; Segs segs;
  int blk = 0, coff = 0;
  for (int i = 0; i < N_IN; i++) {
    ptrs.p[i] = d_in[i];
    const int n = in_sizes[i];
    segs.elems[i] = n;
    segs.start[i] = blk;
    int kind = 0;
    const int R = trows(i);
    if (i == 0) kind = 1;
    else if (i == 8) kind = 2;
    else if (R > 0) kind = 3;
    segs.kind[i] = kind;
    segs.rows[i] = (R > 0) ? R : 1;
    segs.dstoff[i] = coff;
    if (kind == 0 || kind == 3) coff += (n + 7) & ~7;
    if (kind != 2) blk += (n + 1023) / 1024;
  }
  const int total_blk = blk;

  char* ws = (char*)d_ws;
  size_t off = 0;
  auto alloc = [&](size_t bytes)->char*{
    char* p = ws + off; off += (bytes + 255) & ~(size_t)255; return p;
  };
  int*   flag   = (int*)alloc(256);
  bf16*  canon  = (bf16*)alloc((size_t)coff*2);
  float* srcf   = (float*)alloc((size_t)1048576*4);
  bf16*  srcb   = (bf16*)alloc((size_t)1048576*2);
  float* cur    = (float*)alloc((size_t)1048576*4);
  bf16*  curb   = (bf16*)alloc((size_t)1048576*2);
  float* xattn  = (float*)alloc((size_t)1114112*4);
  bf16*  xattnb = (bf16*)alloc((size_t)1114112*2);
  float* pe     = (float*)alloc((size_t)135136*4);
  float* lsum   = (float*)alloc((size_t)8*2048*4);
  float* hid    = (float*)alloc((size_t)5505024*4);  // xna(2.36M) | na-partials(1.58M); down-partials(2.1M)
  bf16*  hidb   = (bf16*)alloc((size_t)5242880*2);
  bf16*  t1b    = (bf16*)alloc((size_t)1048576*2);
  float* v96    = (float*)alloc((size_t)196608*4);
  float* uT     = (float*)alloc((size_t)512*2080*4);
  bf16*  xcT    = (bf16*)alloc((size_t)835584*2);
  bf16*  vcT    = (bf16*)alloc((size_t)208896*2);
  bf16*  attnw  = (bf16*)alloc((size_t)35651584*2);
  if (off > ws_size) return;
  float* napart = hid + 2359296;   // after xna region

  auto Wb = [&](int i)->const bf16*{ return canon + segs.dstoff[i]; };

  float* out0    = (float*)d_out;
  float* out_key = out0 + 1048576;
  float* out_nl  = out_key + 32768;
  float* out_v1  = out_nl + 49152;
  float* out_v2  = out_v1 + 12288;
  float* out_c1  = out_v2 + 12288;
  float* out_c2  = out_c1 + 15360;

  detect_kernel<<<1, 64, 0, stream>>>((const unsigned short*)d_in[0], flag);
  ingest_kernel<<<total_blk, 256, 0, stream>>>(ptrs, segs, flag, canon, srcf, srcb);
  zero_kernel<<<64, 256, 0, stream>>>(lsum, 8*2048);

  auto G = [&](const bf16* A, int wi, int bi, const float* res,
               float* Cf, bf16* Cb, int N, int K, int act){
    const bf16* bias = (bi >= 0) ? Wb(bi) : nullptr;
    dim3 g((N+63)/64, 2048/64);
    if (K % 64 == 0) {
      if (act) mfma_gemm64b<1><<<g, 256, 0, stream>>>(A, Wb(wi), bias, res, Cf, Cb, 2048, N, K);
      else     mfma_gemm64b<0><<<g, 256, 0, stream>>>(A, Wb(wi), bias, res, Cf, Cb, 2048, N, K);
    } else {
      if (act) mfma_gemm64<1><<<g, 256, 0, stream>>>(A, Wb(wi), bias, res, Cf, Cb, 2048, N, K);
      else     mfma_gemm64<0><<<g, 256, 0, stream>>>(A, Wb(wi), bias, res, Cf, Cb, 2048, N, K);
    }
  };

  auto Gdown = [&](const bf16* A, int wi, int bi, const float* res,
                   const bf16* bms, float* Cf, bf16* Cb, int K){
    gemm_chunk64<<<dim3(8, 32, 2), 256, 0, stream>>>(A, Wb(wi), hid, 512, K, K/2);
    down_epi_kernel<<<4096, 256, 0, stream>>>(hid, 2, Wb(bi), res, srcf, bms, Cf, Cb);
  };

  pe_kernel<<<(POS_N*32+255)/256, 256, 0, stream>>>(Wb(1), Wb(11), pe);
  G(srcb, 9, 10, nullptr, xattn, xattnb, 544, 512, 0);
  newkey_kernel<<<128, 256, 0, stream>>>(xattn, out_key);
  attn_exp_mfma<<<dim3(34,32,8), 256, 0, stream>>>(xattnb, xattn, Wb(2), pe, lsum, attnw);
  // ff1
  G(srcb, 12, 13, nullptr, nullptr, hidb, 1536, 512, 1);
  Gdown(hidb, 14, 15, srcf, nullptr, cur, curb, 1536);
  // nonlin attention
  G(curb, 24, 25, nullptr, hid, nullptr, 1152, 512, 0);
  na_mid_kernel<<<dim3(68,12), 256, 0, stream>>>(hid, Wb(3), xcT, out_nl);
  gemm_chunk64<<<dim3(6,32,2), 256, 0, stream>>>(attnw, xcT, napart, ATT_N, KV_LEN, 1088);
  na_epi_kernel<<<(S_LEN*ATT_N+255)/256, 256, 0, stream>>>(napart, hid, lsum, t1b);
  G(t1b, 26, 27, cur, cur, curb, 512, 384, 0);
  // self-attn 1
  G(curb, 28, 29, nullptr, v96, nullptr, 96, 512, 0);
  vc_build_kernel<<<(KV_LEN*96+255)/256, 256, 0, stream>>>(v96, Wb(4), vcT, out_v1);
  apply_gemm<<<dim3(32,8), 256, 0, stream>>>(attnw, vcT, lsum, t1b);
  G(t1b, 30, 31, cur, cur, curb, 512, 96, 0);
  // conv 1
  G(curb, 36, 37, nullptr, hid, nullptr, 1024, 512, 0);
  conv_glu_kernel<<<dim3(64,16), 256, 0, stream>>>(hid, uT, out_c1);
  dwconv_kernel<<<dim3(8,512), 256, 0, stream>>>(uT, Wb(6), Wb(38), Wb(39), t1b);
  G(t1b, 40, 41, cur, cur, curb, 512, 512, 0);
  // ff2 (mid-bypass fused into epilogue)
  G(curb, 16, 17, nullptr, nullptr, hidb, 2048, 512, 1);
  Gdown(hidb, 18, 19, cur, Wb(50), cur, curb, 2048);
  // self-attn 2
  G(curb, 32, 33, nullptr, v96, nullptr, 96, 512, 0);
  vc_build_kernel<<<(KV_LEN*96+255)/256, 256, 0, stream>>>(v96, Wb(5), vcT, out_v2);
  apply_gemm<<<dim3(32,8), 256, 0, stream>>>(attnw, vcT, lsum, t1b);
  G(t1b, 34, 35, cur, cur, curb, 512, 96, 0);
  // conv 2
  G(curb, 42, 43, nullptr, hid, nullptr, 1024, 512, 0);
  conv_glu_kernel<<<dim3(64,16), 256, 0, stream>>>(hid, uT, out_c2);
  dwconv_kernel<<<dim3(8,512), 256, 0, stream>>>(uT, Wb(7), Wb(44), Wb(45), t1b);
  G(t1b, 46, 47, cur, cur, curb, 512, 512, 0);
  // ff3
  G(curb, 20, 21, nullptr, nullptr, hidb, 2560, 512, 1);
  Gdown(hidb, 22, 23, cur, nullptr, cur, curb, 2560);
  final_kernel<<<2048, 256, 0, stream>>>(cur, srcf, Wb(48), Wb(49), Wb(51), out0);
}

// Round 6
// 563.163 us; speedup vs baseline: 1.0084x; 1.0084x over previous
//
#include <hip/hip_runtime.h>
#include <hip/hip_bf16.h>

typedef __hip_bfloat16 bf16;
typedef __attribute__((ext_vector_type(8))) short bf16x8;
typedef __attribute__((ext_vector_type(4))) float f32x4;

constexpr int S_LEN  = 2048;
constexpr int D_DIM  = 512;
constexpr int KV_LEN = 2176;   // S + L
constexpr int L_LEN  = 128;
constexpr int POS_N  = 4223;   // S + KV - 1
constexpr int ATT_N  = 384;
constexpr int N_IN   = 52;

__device__ __forceinline__ float b2f(bf16 v){ return __bfloat162float(v); }
__device__ __forceinline__ bf16  f2b(float v){ return __float2bfloat16(v); }
__device__ __forceinline__ unsigned short f2bu(float v){
  bf16 h = __float2bfloat16(v);
  return *(unsigned short*)&h;
}

__device__ __forceinline__ float softplus_f(float x){
  return (x > 15.0f) ? x : __logf(1.0f + __expf(x));
}
__device__ __forceinline__ float swoosh_l_f(float x){
  return softplus_f(x - 4.0f) - 0.08f*x - 0.035f;
}
__device__ __forceinline__ float swoosh_r_f(float x){
  return softplus_f(x - 1.0f) - 0.08f*x - 0.313261687f;
}
__device__ __forceinline__ float tanh_fast(float x){
  const float xc = fminf(fmaxf(x, -15.f), 15.f);
  const float t = __expf(2.f*xc);
  return (t - 1.f) / (t + 1.f);
}

__device__ __forceinline__ void gload4(const float* p, float* d){
  const float4 v = *(const float4*)p;
  d[0]=v.x; d[1]=v.y; d[2]=v.z; d[3]=v.w;
}
__device__ __forceinline__ void gload4(const bf16* p, float* d){
  union { unsigned long long q; unsigned short u[4]; } w;
  w.q = *(const unsigned long long*)p;
  d[0] = __uint_as_float((unsigned)w.u[0] << 16);
  d[1] = __uint_as_float((unsigned)w.u[1] << 16);
  d[2] = __uint_as_float((unsigned)w.u[2] << 16);
  d[3] = __uint_as_float((unsigned)w.u[3] << 16);
}

// ============ dtype detect + ingest ============
__global__ void detect_kernel(const unsigned short* __restrict__ src_u16, int* __restrict__ flag){
  int wild = 0;
  for (int i = threadIdx.x; i < 1024; i += 64) {
    float v = __uint_as_float((unsigned)src_u16[i] << 16);
    if (!(fabsf(v) <= 1e10f)) wild++;
  }
  #pragma unroll
  for (int off=32; off; off>>=1) wild += __shfl_down(wild, off);
  if (threadIdx.x == 0) *flag = (wild > 16) ? 1 : 0;
}

struct Ptrs { const void* p[N_IN]; };
struct Segs { int start[N_IN]; int elems[N_IN]; int kind[N_IN]; int dstoff[N_IN]; int rows[N_IN]; };
// kind: 0 = to canonical bf16; 1 = src -> fp32 srcf + bf16 srcb; 2 = skip;
//       3 = transpose [rows x cols] -> bf16 [cols x rows] at dstoff (LDS-tiled, 32x32).

__global__ void ingest_kernel(Ptrs ptrs, Segs segs, const int* __restrict__ flag,
                              bf16* __restrict__ canon, float* __restrict__ srcf,
                              bf16* __restrict__ srcb){
  const int f = *flag;   // 1 = fp32 source, 0 = bf16 source (uniform branch)
  const int b = blockIdx.x;
  const int tid = threadIdx.x;
  int t = 0;
  #pragma unroll 1
  for (int i = 1; i < N_IN; i++) if (b >= segs.start[i]) t = i;
  const int kind = segs.kind[t];
  if (kind == 2) return;
  const int n = segs.elems[t];
  const void* sp = ptrs.p[t];

  if (kind == 3) {
    __shared__ float tile[32][33];
    const int R = segs.rows[t];
    const int C = n / R;
    const int ctiles = C >> 5;
    const int tb = b - segs.start[t];
    const int ri = tb / ctiles, ci = tb - ri*ctiles;
    const int r0 = ri << 5, c0 = ci << 5;
    const int row = tid >> 3, cg = tid & 7;
    float v[4];
    if (f) gload4((const float*)sp + (size_t)(r0+row)*C + c0 + cg*4, v);
    else   gload4((const bf16*)sp  + (size_t)(r0+row)*C + c0 + cg*4, v);
    tile[cg*4+0][row] = v[0]; tile[cg*4+1][row] = v[1];
    tile[cg*4+2][row] = v[2]; tile[cg*4+3][row] = v[3];
    __syncthreads();
    ushort4 o;
    o.x = f2bu(tile[row][cg*4+0]); o.y = f2bu(tile[row][cg*4+1]);
    o.z = f2bu(tile[row][cg*4+2]); o.w = f2bu(tile[row][cg*4+3]);
    *(ushort4*)&canon[segs.dstoff[t] + (size_t)(c0+row)*R + r0 + cg*4] = o;
    return;
  }

  const int base = (b - segs.start[t]) * 1024 + tid * 4;
  #pragma unroll
  for (int k = 0; k < 4; k++) {
    const int e = base + k;
    if (e >= n) break;
    float v;
    if (f) v = ((const float*)sp)[e];
    else   v = b2f(((const bf16*)sp)[e]);
    if (kind == 1) { srcf[e] = v; srcb[e] = f2b(v); }
    else canon[segs.dstoff[t] + e] = f2b(v);
  }
}

// ---- MFMA GEMM 64x64 tile, BK=64, dbuf LDS, prefetch-2 global loads ----
template<int ACT>
__global__ __launch_bounds__(256) void mfma_gemm64b(
    const bf16* __restrict__ A, const bf16* __restrict__ Bt,
    const bf16* __restrict__ bias, const float* __restrict__ residual,
    float* __restrict__ Cf, bf16* __restrict__ Cb, int M, int N, int K)
{
  __shared__ __align__(16) short As[2][64*72];
  __shared__ __align__(16) short Bs[2][64*72];
  const int tid = threadIdx.x;
  const int wave = tid >> 6, lane = tid & 63;
  const int l15 = lane & 15, quad = lane >> 4;
  const int m0 = blockIdx.y*64, n0 = blockIdx.x*64;

  f32x4 acc[4];
  #pragma unroll
  for (int nt=0;nt<4;nt++) acc[nt] = (f32x4){0.f,0.f,0.f,0.f};

  const int arow = tid >> 2, aoff = (tid & 3) * 16;
  const bf16* aptr = A + (size_t)(m0 + arow)*K + aoff;
  const bf16* bptr = (n0 + arow < N) ? (Bt + (size_t)(n0 + arow)*K + aoff) : nullptr;

  uint4 pa0 = *(const uint4*)(aptr);
  uint4 pa1 = *(const uint4*)(aptr + 8);
  uint4 pb0 = make_uint4(0u,0u,0u,0u), pb1 = make_uint4(0u,0u,0u,0u);
  if (bptr) { pb0 = *(const uint4*)(bptr); pb1 = *(const uint4*)(bptr + 8); }
  uint4 qa0 = pa0, qa1 = pa1, qb0 = pb0, qb1 = pb1;
  if (K > 64) {
    qa0 = *(const uint4*)(aptr + 64);
    qa1 = *(const uint4*)(aptr + 72);
    if (bptr) { qb0 = *(const uint4*)(bptr + 64); qb1 = *(const uint4*)(bptr + 72); }
  }

  int p = 0;
  for (int k0 = 0; k0 < K; k0 += 64) {
    *(uint4*)&As[p][arow*72 + aoff]     = pa0;
    *(uint4*)&As[p][arow*72 + aoff + 8] = pa1;
    *(uint4*)&Bs[p][arow*72 + aoff]     = pb0;
    *(uint4*)&Bs[p][arow*72 + aoff + 8] = pb1;
    __syncthreads();
    pa0 = qa0; pa1 = qa1; pb0 = qb0; pb1 = qb1;
    if (k0 + 128 < K) {
      qa0 = *(const uint4*)(aptr + k0 + 128);
      qa1 = *(const uint4*)(aptr + k0 + 136);
      if (bptr) { qb0 = *(const uint4*)(bptr + k0 + 128); qb1 = *(const uint4*)(bptr + k0 + 136); }
    }
    bf16x8 af0 = *(const bf16x8*)&As[p][(wave*16 + l15)*72 +      quad*8];
    bf16x8 af1 = *(const bf16x8*)&As[p][(wave*16 + l15)*72 + 32 + quad*8];
    #pragma unroll
    for (int nt=0;nt<4;nt++){
      bf16x8 b0 = *(const bf16x8*)&Bs[p][(nt*16 + l15)*72 +      quad*8];
      bf16x8 b1 = *(const bf16x8*)&Bs[p][(nt*16 + l15)*72 + 32 + quad*8];
      acc[nt] = __builtin_amdgcn_mfma_f32_16x16x32_bf16(af0, b0, acc[nt], 0,0,0);
      acc[nt] = __builtin_amdgcn_mfma_f32_16x16x32_bf16(af1, b1, acc[nt], 0,0,0);
    }
    p ^= 1;
  }

  #pragma unroll
  for (int nt=0;nt<4;nt++){
    const int col = n0 + nt*16 + l15;
    if (col >= N) continue;
    const float bb = bias ? b2f(bias[col]) : 0.f;
    #pragma unroll
    for (int r=0;r<4;r++){
      const int row = m0 + wave*16 + quad*4 + r;
      float v = acc[nt][r] + bb;
      if (ACT == 1) v = swoosh_l_f(v);
      const size_t ci = (size_t)row*N + col;
      if (residual) v += residual[ci];
      if (Cf) Cf[ci] = v;
      if (Cb) Cb[ci] = f2b(v);
    }
  }
}

// ---- MFMA GEMM 64x64 tile, BK=32 (for K not divisible by 64) ----
template<int ACT>
__global__ __launch_bounds__(256) void mfma_gemm64(
    const bf16* __restrict__ A, const bf16* __restrict__ Bt,
    const bf16* __restrict__ bias, const float* __restrict__ residual,
    float* __restrict__ Cf, bf16* __restrict__ Cb, int M, int N, int K)
{
  __shared__ __align__(16) short As[2][64*40];
  __shared__ __align__(16) short Bs[2][64*40];
  const int tid = threadIdx.x;
  const int wave = tid >> 6, lane = tid & 63;
  const int l15 = lane & 15, quad = lane >> 4;
  const int m0 = blockIdx.y*64, n0 = blockIdx.x*64;

  f32x4 acc[4];
  #pragma unroll
  for (int nt=0;nt<4;nt++) acc[nt] = (f32x4){0.f,0.f,0.f,0.f};

  const int arow = tid >> 2, aoff = (tid & 3) * 8;
  const bf16* aptr = A + (size_t)(m0 + arow)*K + aoff;
  const bf16* bptr = (n0 + arow < N) ? (Bt + (size_t)(n0 + arow)*K + aoff) : nullptr;

  uint4 av = *(const uint4*)(aptr);
  uint4 bv = make_uint4(0u,0u,0u,0u);
  if (bptr) bv = *(const uint4*)(bptr);

  int p = 0;
  for (int k0 = 0; k0 < K; k0 += 32) {
    *(uint4*)&As[p][arow*40 + aoff] = av;
    *(uint4*)&Bs[p][arow*40 + aoff] = bv;
    __syncthreads();
    if (k0 + 32 < K) {
      av = *(const uint4*)(aptr + k0 + 32);
      if (bptr) bv = *(const uint4*)(bptr + k0 + 32);
    }
    bf16x8 af = *(const bf16x8*)&As[p][(wave*16 + l15)*40 + quad*8];
    #pragma unroll
    for (int nt=0;nt<4;nt++){
      bf16x8 bfr = *(const bf16x8*)&Bs[p][(nt*16 + l15)*40 + quad*8];
      acc[nt] = __builtin_amdgcn_mfma_f32_16x16x32_bf16(af, bfr, acc[nt], 0,0,0);
    }
    p ^= 1;
  }

  #pragma unroll
  for (int nt=0;nt<4;nt++){
    const int col = n0 + nt*16 + l15;
    if (col >= N) continue;
    const float bb = bias ? b2f(bias[col]) : 0.f;
    #pragma unroll
    for (int r=0;r<4;r++){
      const int row = m0 + wave*16 + quad*4 + r;
      float v = acc[nt][r] + bb;
      if (ACT == 1) v = swoosh_l_f(v);
      const size_t ci = (size_t)row*N + col;
      if (residual) v += residual[ci];
      if (Cf) Cf[ci] = v;
      if (Cb) Cb[ci] = f2b(v);
    }
  }
}

// ---- K-chunked GEMM, BK=64, prefetch-2: plain stores into per-z slices ----
__global__ __launch_bounds__(256) void gemm_chunk64(
    const bf16* __restrict__ A, const bf16* __restrict__ Bt,
    float* __restrict__ C, int N, int K, int kLen)
{
  __shared__ __align__(16) short As[2][64*72];
  __shared__ __align__(16) short Bs[2][64*72];
  const int tid = threadIdx.x;
  const int wave = tid >> 6, lane = tid & 63;
  const int l15 = lane & 15, quad = lane >> 4;
  const int n0 = blockIdx.x*64, m0 = blockIdx.y*64;
  const int kBeg = blockIdx.z * kLen;

  f32x4 acc[4];
  #pragma unroll
  for (int nt=0;nt<4;nt++) acc[nt] = (f32x4){0.f,0.f,0.f,0.f};

  const int arow = tid >> 2, aoff = (tid & 3) * 16;
  const bf16* aptr = A + (size_t)(m0 + arow)*K + kBeg + aoff;
  const bf16* bptr = Bt + (size_t)(n0 + arow)*K + kBeg + aoff;

  uint4 pa0 = *(const uint4*)(aptr);
  uint4 pa1 = *(const uint4*)(aptr + 8);
  uint4 pb0 = *(const uint4*)(bptr);
  uint4 pb1 = *(const uint4*)(bptr + 8);
  uint4 qa0 = pa0, qa1 = pa1, qb0 = pb0, qb1 = pb1;
  if (kLen > 64) {
    qa0 = *(const uint4*)(aptr + 64);
    qa1 = *(const uint4*)(aptr + 72);
    qb0 = *(const uint4*)(bptr + 64);
    qb1 = *(const uint4*)(bptr + 72);
  }

  int p = 0;
  for (int k0 = 0; k0 < kLen; k0 += 64) {
    *(uint4*)&As[p][arow*72 + aoff]     = pa0;
    *(uint4*)&As[p][arow*72 + aoff + 8] = pa1;
    *(uint4*)&Bs[p][arow*72 + aoff]     = pb0;
    *(uint4*)&Bs[p][arow*72 + aoff + 8] = pb1;
    __syncthreads();
    pa0 = qa0; pa1 = qa1; pb0 = qb0; pb1 = qb1;
    if (k0 + 128 < kLen) {
      qa0 = *(const uint4*)(aptr + k0 + 128);
      qa1 = *(const uint4*)(aptr + k0 + 136);
      qb0 = *(const uint4*)(bptr + k0 + 128);
      qb1 = *(const uint4*)(bptr + k0 + 136);
    }
    bf16x8 af0 = *(const bf16x8*)&As[p][(wave*16 + l15)*72 +      quad*8];
    bf16x8 af1 = *(const bf16x8*)&As[p][(wave*16 + l15)*72 + 32 + quad*8];
    #pragma unroll
    for (int nt=0;nt<4;nt++){
      bf16x8 b0 = *(const bf16x8*)&Bs[p][(nt*16 + l15)*72 +      quad*8];
      bf16x8 b1 = *(const bf16x8*)&Bs[p][(nt*16 + l15)*72 + 32 + quad*8];
      acc[nt] = __builtin_amdgcn_mfma_f32_16x16x32_bf16(af0, b0, acc[nt], 0,0,0);
      acc[nt] = __builtin_amdgcn_mfma_f32_16x16x32_bf16(af1, b1, acc[nt], 0,0,0);
    }
    p ^= 1;
  }

  float* Cz = C + (size_t)blockIdx.z * (size_t)S_LEN * N;
  #pragma unroll
  for (int nt=0;nt<4;nt++){
    const int col = n0 + nt*16 + l15;
    #pragma unroll
    for (int r=0;r<4;r++){
      const int row = m0 + wave*16 + quad*4 + r;
      Cz[(size_t)row*N + col] = acc[nt][r];
    }
  }
}

// ---- down-proj epilogue: sum 2 K-chunks + bias + residual (+ optional mid-bypass) ----
__global__ void down_epi_kernel(const float* __restrict__ gacc, int chunks,
                                const bf16* __restrict__ bias, const float* __restrict__ res,
                                const float* __restrict__ srcf, const bf16* __restrict__ bms,
                                float* __restrict__ outf, bf16* __restrict__ outb){
  int idx = blockIdx.x*256 + threadIdx.x;
  if (idx >= S_LEN*D_DIM) return;
  float v = gacc[idx];
  #pragma unroll 1
  for (int z=1; z<chunks; z++) v += gacc[idx + (size_t)z*S_LEN*D_DIM];
  v += b2f(bias[idx & 511]) + res[idx];
  if (bms) {
    const float o = srcf[idx];
    v = o + (v - o)*b2f(bms[idx & 511]);
  }
  outf[idx] = v;
  outb[idx] = f2b(v);
}

// ---- nonlin-attn epilogue: sum 2 K-chunks, gate, normalize ----
__global__ void na_epi_kernel(const float* __restrict__ part, const float* __restrict__ xna,
                              const float* __restrict__ l0, bf16* __restrict__ t1b){
  int idx = blockIdx.x*256 + threadIdx.x;
  if (idx >= S_LEN*ATT_N) return;
  const int SL = S_LEN*ATT_N;
  float v = part[idx] + part[idx+SL];
  int s = idx / ATT_N, c = idx - s*ATT_N;
  t1b[idx] = f2b(v * xna[(size_t)s*1152 + 768 + c] / l0[s]);
}

// ---- attention apply: barrier-free, LDS-free, direct-to-register MFMA ----
__global__ __launch_bounds__(256) void apply_gemm(
    const bf16* __restrict__ attnw, const bf16* __restrict__ vcT,
    const float* __restrict__ l, bf16* __restrict__ o)
{
  const int h = blockIdx.y;
  const int m0 = blockIdx.x*64;
  const int tid = threadIdx.x;
  const int wave = tid >> 6, lane = tid & 63;
  const int l15 = lane & 15, quad = lane >> 4;
  const int vr = (l15 < 12) ? l15 : 11;   // clamp unused B cols in-bounds

  const bf16* aptr = attnw + ((size_t)h*S_LEN + m0 + wave*16 + l15)*KV_LEN + quad*8;
  const bf16* bptr = vcT   + ((size_t)h*12 + vr)*KV_LEN + quad*8;

  f32x4 acc = (f32x4){0.f,0.f,0.f,0.f};
  #pragma unroll 1
  for (int k0 = 0; k0 < KV_LEN; k0 += 128) {   // 17 groups of 4 MFMA
    bf16x8 a0 = *(const bf16x8*)(aptr + k0);
    bf16x8 a1 = *(const bf16x8*)(aptr + k0 + 32);
    bf16x8 a2 = *(const bf16x8*)(aptr + k0 + 64);
    bf16x8 a3 = *(const bf16x8*)(aptr + k0 + 96);
    bf16x8 b0 = *(const bf16x8*)(bptr + k0);
    bf16x8 b1 = *(const bf16x8*)(bptr + k0 + 32);
    bf16x8 b2 = *(const bf16x8*)(bptr + k0 + 64);
    bf16x8 b3 = *(const bf16x8*)(bptr + k0 + 96);
    acc = __builtin_amdgcn_mfma_f32_16x16x32_bf16(a0, b0, acc, 0,0,0);
    acc = __builtin_amdgcn_mfma_f32_16x16x32_bf16(a1, b1, acc, 0,0,0);
    acc = __builtin_amdgcn_mfma_f32_16x16x32_bf16(a2, b2, acc, 0,0,0);
    acc = __builtin_amdgcn_mfma_f32_16x16x32_bf16(a3, b3, acc, 0,0,0);
  }

  if (l15 < 12) {
    #pragma unroll
    for (int r=0;r<4;r++){
      const int row = m0 + wave*16 + quad*4 + r;
      o[(size_t)row*96 + h*12 + l15] = f2b(acc[r] / l[(size_t)h*S_LEN + row]);
    }
  }
}

// ---- pe + lsum zero (folded) ----
__global__ void pe_kernel(const bf16* __restrict__ pos_emb, const bf16* __restrict__ pos_w,
                          float* __restrict__ pe, float* __restrict__ lsum){
  int idx = blockIdx.x*256 + threadIdx.x;
  if (idx < 8*2048) lsum[idx] = 0.f;
  if (idx >= POS_N*32) return;
  int p = idx >> 5, j = idx & 31;
  float acc = 0.f;
  #pragma unroll 8
  for (int d=0; d<48; d++) acc += b2f(pos_emb[p*48+d]) * b2f(pos_w[d*32+j]);
  pe[idx] = acc;
}

__global__ void newkey_kernel(const float* __restrict__ xattn, float* __restrict__ out){
  int idx = blockIdx.x*256 + threadIdx.x;
  if (idx >= 128*256) return;
  int r = idx >> 8, c = idx & 255;
  out[idx] = xattn[(size_t)(1912+r)*544 + 256 + c];
}

// ======== single-pass attention weights, QK^T on MFMA, coalesced stores ========
__global__ __launch_bounds__(256) void attn_exp_mfma(
    const bf16* __restrict__ xattnb, const float* __restrict__ xattn,
    const bf16* __restrict__ cached_key, const float* __restrict__ pe,
    float* __restrict__ l, bf16* __restrict__ attnw)
{
  const int h = blockIdx.z;
  const int t0 = blockIdx.x * 64;
  const int s0 = blockIdx.y * 64;
  __shared__ __align__(16) short QK[2*64*40];   // Qs | Ks ; reused for score staging
  short* Qs = QK;
  short* Ks = QK + 64*40;
  __shared__ __align__(16) float4 Psf[64];
  __shared__ __align__(16) float4 Pwf[127*5];
  const int tid = threadIdx.x;
  const int wave = tid >> 6, lane = tid & 63;
  const int l15 = lane & 15, quad = lane >> 4;

  {
    const int r = tid >> 2, cg = tid & 3;
    *(uint4*)&Qs[r*40 + cg*8] =
      *(const uint4*)(xattnb + (size_t)(s0+r)*544 + h*32 + cg*8);
  }
  {
    const int r = tid >> 2, cg = tid & 3;
    uint4 kv;
    if (t0 < L_LEN) kv = *(const uint4*)(cached_key + (size_t)(t0+r)*256 + h*32 + cg*8);
    else            kv = *(const uint4*)(xattnb + (size_t)(t0+r-L_LEN)*544 + 256 + h*32 + cg*8);
    *(uint4*)&Ks[r*40 + cg*8] = kv;
  }
  if (tid < 64) Psf[tid] = *(const float4*)(xattn + (size_t)(s0+tid)*544 + 512 + h*4);
  const int pbase = s0 - t0 + KV_LEN - 1 - 63;
  if (tid < 127) Pwf[tid*5] = *(const float4*)(pe + (size_t)(pbase+tid)*32 + h*4);
  __syncthreads();

  bf16x8 af = *(const bf16x8*)&Qs[(wave*16 + l15)*40 + quad*8];
  bf16x8 bfr[4];
  #pragma unroll
  for (int nt=0;nt<4;nt++) bfr[nt] = *(const bf16x8*)&Ks[(nt*16 + l15)*40 + quad*8];
  f32x4 acc[4];
  #pragma unroll
  for (int nt=0;nt<4;nt++)
    acc[nt] = __builtin_amdgcn_mfma_f32_16x16x32_bf16(af, bfr[nt], (f32x4){0.f,0.f,0.f,0.f}, 0,0,0);

  // epilogue compute: scores -> exp, keep in regs, row sums
  float rowsum[4] = {0.f,0.f,0.f,0.f};
  unsigned short ev[4][4];
  #pragma unroll
  for (int nt=0;nt<4;nt++){
    const int tl = nt*16 + l15;
    #pragma unroll
    for (int r=0;r<4;r++){
      const int sl = wave*16 + quad*4 + r;
      const float4 pv = Psf[sl];
      const float4 pp = Pwf[(sl - tl + 63)*5];
      const float sc = acc[nt][r]*0.17677669529663687f
                     + pv.x*pp.x + pv.y*pp.y + pv.z*pp.z + pv.w*pp.w;
      const float e = __expf(sc - 12.0f);
      rowsum[r] += e;
      ev[nt][r] = f2bu(e);
    }
  }
  #pragma unroll
  for (int r=0;r<4;r++){
    float rs = rowsum[r];
    #pragma unroll
    for (int msk = 1; msk < 16; msk <<= 1) rs += __shfl_xor(rs, msk);
    if (l15 == 0) {
      const int sg = s0 + wave*16 + quad*4 + r;
      atomicAdd(&l[(size_t)h*S_LEN + sg], rs);
    }
  }

  // stage score tile in LDS (reuse QK region), then coalesced 16B stores
  __syncthreads();
  unsigned short* Sc = (unsigned short*)QK;   // 64 rows x 72 stride (144B, 16B-aligned)
  #pragma unroll
  for (int nt=0;nt<4;nt++){
    const int tl = nt*16 + l15;
    #pragma unroll
    for (int r=0;r<4;r++){
      Sc[(wave*16 + quad*4 + r)*72 + tl] = ev[nt][r];
    }
  }
  __syncthreads();
  const int sr = tid >> 2, cg = tid & 3;
  const uint4 w0 = *(const uint4*)&Sc[sr*72 + cg*16];
  const uint4 w1 = *(const uint4*)&Sc[sr*72 + cg*16 + 8];
  bf16* orow = attnw + ((size_t)h*S_LEN + s0 + sr)*KV_LEN + t0 + cg*16;
  *(uint4*)orow = w0;
  *(uint4*)(orow + 8) = w1;
}

// ---- nonlin-attn mid: LDS-tiled transpose, 32x32 per block ----
// grid (68 t-tiles, 12 c-tiles)
__global__ __launch_bounds__(256) void na_mid_kernel(
    const float* __restrict__ xna, const bf16* __restrict__ cached,
    bf16* __restrict__ xcT, float* __restrict__ out_nl)
{
  __shared__ float tile[32][33];
  const int t0 = blockIdx.x*32, c0 = blockIdx.y*32;
  const int tid = threadIdx.x;
  const int row = tid >> 3, cg = tid & 7;
  const int t = t0 + row;
  float v[4];
  if (t < L_LEN) {
    gload4(cached + (size_t)t*ATT_N + c0 + cg*4, v);
  } else {
    const int s = t - L_LEN;
    const float4 sv = *(const float4*)(xna + (size_t)s*1152 + c0 + cg*4);
    const float4 xv = *(const float4*)(xna + (size_t)s*1152 + 384 + c0 + cg*4);
    v[0] = xv.x * tanh_fast(sv.x); v[1] = xv.y * tanh_fast(sv.y);
    v[2] = xv.z * tanh_fast(sv.z); v[3] = xv.w * tanh_fast(sv.w);
    if (t >= 2040 && t < 2168)
      *(float4*)(out_nl + (size_t)(t-2040)*ATT_N + c0 + cg*4) = make_float4(v[0],v[1],v[2],v[3]);
  }
  tile[cg*4+0][row] = v[0]; tile[cg*4+1][row] = v[1];
  tile[cg*4+2][row] = v[2]; tile[cg*4+3][row] = v[3];
  __syncthreads();
  ushort4 o;
  o.x = f2bu(tile[row][cg*4+0]); o.y = f2bu(tile[row][cg*4+1]);
  o.z = f2bu(tile[row][cg*4+2]); o.w = f2bu(tile[row][cg*4+3]);
  *(ushort4*)&xcT[(size_t)(c0+row)*KV_LEN + t0 + cg*4] = o;
}

__global__ void vc_build_kernel(const float* __restrict__ v96, const bf16* __restrict__ cached,
                                bf16* __restrict__ vcT, float* __restrict__ out_v){
  int idx = blockIdx.x*256 + threadIdx.x;
  if (idx >= KV_LEN*96) return;
  int c = idx / KV_LEN, t = idx - c*KV_LEN;
  float v;
  if (t < L_LEN) { vcT[idx] = cached[t*96 + c]; return; }
  v = v96[(size_t)(t-L_LEN)*96 + c];
  vcT[idx] = f2b(v);
  if (t >= 2040 && t < 2168) out_v[(t-2040)*96 + c] = v;
}

// ---- conv GLU: LDS-tiled transpose into uT (stride 2080, data at offset 32) ----
// grid (64 s-tiles, 16 c-tiles)
__global__ __launch_bounds__(256) void conv_glu_kernel(
    const float* __restrict__ xcv, float* __restrict__ uT, float* __restrict__ out_c)
{
  __shared__ float tile[32][33];
  const int s0 = blockIdx.x*32, c0 = blockIdx.y*32;
  const int tid = threadIdx.x;
  const int row = tid >> 3, cg = tid & 7;
  const int s = s0 + row;
  const float* base = xcv + (size_t)s*1024 + c0 + cg*4;
  const float4 a = *(const float4*)base;
  const float4 g = *(const float4*)(base + 512);
  float v[4];
  v[0] = a.x / (1.0f + __expf(-g.x)); v[1] = a.y / (1.0f + __expf(-g.y));
  v[2] = a.z / (1.0f + __expf(-g.z)); v[3] = a.w / (1.0f + __expf(-g.w));
  if (s >= 2010 && s < 2040) {
    #pragma unroll
    for (int j=0;j<4;j++) out_c[(c0+cg*4+j)*30 + (s-2010)] = v[j];
  }
  tile[cg*4+0][row] = v[0]; tile[cg*4+1][row] = v[1];
  tile[cg*4+2][row] = v[2]; tile[cg*4+3][row] = v[3];
  __syncthreads();
  const float4 w = make_float4(tile[row][cg*4+0], tile[row][cg*4+1],
                               tile[row][cg*4+2], tile[row][cg*4+3]);
  *(float4*)&uT[(size_t)(c0+row)*2080 + 32 + s0 + cg*4] = w;
}

// ---- depthwise conv, tiled 64s x 32c, register window, coalesced stores ----
// grid (32 s-blocks, 16 c-blocks), 256 threads. Replaces the per-channel
// variant whose y-stores were 2B scatters at 1KB stride (≈32x write granule
// amplification). Output staged in LDS, written 16B/lane, 64B/row.
__global__ __launch_bounds__(256) void dwconv_kernel(const float* __restrict__ uT,
    const bf16* __restrict__ cached,
    const bf16* __restrict__ dww, const bf16* __restrict__ dwb, bf16* __restrict__ y){
  __shared__ float win[32][97];            // 32 c-rows x 94 s (pad 97 vs bank conflicts)
  __shared__ float wts[32][33];            // 31 taps (pad 33)
  __shared__ unsigned short ost[64][34];   // 64 s-rows x 32 c (pad 34)
  const int s0 = blockIdx.x * 64, c0 = blockIdx.y * 32;
  const int tid = threadIdx.x;

  {  // window load: y[s] needs u-index 2+s..2+s+30 -> block needs 94 values from 2+s0
    const int cr = tid >> 3, li = tid & 7;
    for (int i = li; i < 94; i += 8) {
      float v;
      if (s0 == 0 && i < 30) v = b2f(cached[(c0+cr)*30 + i]);
      else                   v = uT[(size_t)(c0+cr)*2080 + 2 + s0 + i];
      win[cr][i] = v;
    }
  }
  for (int i = tid; i < 32*31; i += 256) {
    const int cr = i / 31, j = i - cr*31;
    wts[cr][j] = b2f(dww[(c0+cr)*31 + j]);
  }
  __syncthreads();

  const int cw = tid >> 3;          // channel within tile (0..31)
  const int sb = (tid & 7) * 8;     // s-base within tile (8 outputs/thread)
  float wreg[38];
  #pragma unroll
  for (int i=0;i<38;i++) wreg[i] = win[cw][sb + i];
  float wt[31];
  #pragma unroll
  for (int j=0;j<31;j++) wt[j] = wts[cw][j];
  const float bias = b2f(dwb[c0+cw]);
  #pragma unroll
  for (int k=0;k<8;k++){
    float acc = bias;
    #pragma unroll
    for (int j=0;j<31;j++) acc += wreg[k+j]*wt[j];
    ost[sb+k][cw] = f2bu(swoosh_r_f(acc));
  }
  __syncthreads();

  const int rr = tid >> 2, co = tid & 3;   // 64 rows x 4 x 16B
  const unsigned int* op = (const unsigned int*)&ost[rr][co*8];
  uint4 w4 = make_uint4(op[0], op[1], op[2], op[3]);
  *(uint4*)&y[(size_t)(s0+rr)*512 + c0 + co*8] = w4;
}

__global__ __launch_bounds__(256) void final_kernel(const float* __restrict__ cur,
    const float* __restrict__ srcf, const bf16* __restrict__ nbias,
    const bf16* __restrict__ nls, const bf16* __restrict__ bys, float* __restrict__ out){
  const int s = blockIdx.x, tid = threadIdx.x;
  __shared__ float red[4];
  float p = 0.f;
  for (int c=tid; c<512; c+=256){
    float d = cur[(size_t)s*512+c] - b2f(nbias[c]);
    p += d*d;
  }
  #pragma unroll
  for (int off=32; off; off>>=1) p += __shfl_down(p, off);
  if ((tid & 63) == 0) red[tid>>6] = p;
  __syncthreads();
  const float ms = (red[0]+red[1]+red[2]+red[3]) * (1.0f/512.0f);
  const float scale = expf(b2f(nls[0])) / sqrtf(ms);
  for (int c=tid; c<512; c+=256){
    float v = cur[(size_t)s*512+c]*scale;
    float o = srcf[(size_t)s*512+c];
    out[(size_t)s*512+c] = o + (v-o)*b2f(bys[c]);
  }
}

// =====================================================================
extern "C" void kernel_launch(void* const* d_in, const int* in_sizes, int n_in,
                              void* d_out, int out_size, void* d_ws, size_t ws_size,
                              hipStream_t stream) {
  if (n_in < N_IN) return;

  auto trows = [](int i)->int{
    switch (i) {
      case 14: return 1536; case 18: return 2048; case 22: return 2560;
      case 26: return 384;  case 30: return 96;   case 34: return 96;
      case 9: case 12: case 16: case 20: case 24: case 28: case 32:
      case 36: case 40: case 42: case 46: return 512;
      default: return 0;
    }
  };

  Ptrs ptrs; Segs segs;
  int blk = 0, coff = 0;
  for (int i = 0; i < N_IN; i++) {
    ptrs.p[i] = d_in[i];
    const int n = in_sizes[i];
    segs.elems[i] = n;
    segs.start[i] = blk;
    int kind = 0;
    const int R = trows(i);
    if (i == 0) kind = 1;
    else if (i == 8) kind = 2;
    else if (R > 0) kind = 3;
    segs.kind[i] = kind;
    segs.rows[i] = (R > 0) ? R : 1;
    segs.dstoff[i] = coff;
    if (kind == 0 || kind == 3) coff += (n + 7) & ~7;
    if (kind != 2) blk += (n + 1023) / 1024;
  }
  const int total_blk = blk;

  char* ws = (char*)d_ws;
  size_t off = 0;
  auto alloc = [&](size_t bytes)->char*{
    char* p = ws + off; off += (bytes + 255) & ~(size_t)255; return p;
  };
  int*   flag   = (int*)alloc(256);
  bf16*  canon  = (bf16*)alloc((size_t)coff*2);
  float* srcf   = (float*)alloc((size_t)1048576*4);
  bf16*  srcb   = (bf16*)alloc((size_t)1048576*2);
  float* cur    = (float*)alloc((size_t)1048576*4);
  bf16*  curb   = (bf16*)alloc((size_t)1048576*2);
  float* xattn  = (float*)alloc((size_t)1114112*4);
  bf16*  xattnb = (bf16*)alloc((size_t)1114112*2);
  float* pe     = (float*)alloc((size_t)135136*4);
  float* lsum   = (float*)alloc((size_t)8*2048*4);
  float* hid    = (float*)alloc((size_t)5505024*4);  // xna(2.36M) | na-partials(1.58M); down-partials(2.1M)
  bf16*  hidb   = (bf16*)alloc((size_t)5242880*2);
  bf16*  t1b    = (bf16*)alloc((size_t)1048576*2);
  float* v96    = (float*)alloc((size_t)196608*4);
  float* uT     = (float*)alloc((size_t)512*2080*4);
  bf16*  xcT    = (bf16*)alloc((size_t)835584*2);
  bf16*  vcT    = (bf16*)alloc((size_t)208896*2);
  bf16*  attnw  = (bf16*)alloc((size_t)35651584*2);
  if (off > ws_size) return;
  float* napart = hid + 2359296;   // after xna region

  auto Wb = [&](int i)->const bf16*{ return canon + segs.dstoff[i]; };

  float* out0    = (float*)d_out;
  float* out_key = out0 + 1048576;
  float* out_nl  = out_key + 32768;
  float* out_v1  = out_nl + 49152;
  float* out_v2  = out_v1 + 12288;
  float* out_c1  = out_v2 + 12288;
  float* out_c2  = out_c1 + 15360;

  detect_kernel<<<1, 64, 0, stream>>>((const unsigned short*)d_in[0], flag);
  ingest_kernel<<<total_blk, 256, 0, stream>>>(ptrs, segs, flag, canon, srcf, srcb);

  auto G = [&](const bf16* A, int wi, int bi, const float* res,
               float* Cf, bf16* Cb, int N, int K, int act){
    const bf16* bias = (bi >= 0) ? Wb(bi) : nullptr;
    dim3 g((N+63)/64, 2048/64);
    if (K % 64 == 0) {
      if (act) mfma_gemm64b<1><<<g, 256, 0, stream>>>(A, Wb(wi), bias, res, Cf, Cb, 2048, N, K);
      else     mfma_gemm64b<0><<<g, 256, 0, stream>>>(A, Wb(wi), bias, res, Cf, Cb, 2048, N, K);
    } else {
      if (act) mfma_gemm64<1><<<g, 256, 0, stream>>>(A, Wb(wi), bias, res, Cf, Cb, 2048, N, K);
      else     mfma_gemm64<0><<<g, 256, 0, stream>>>(A, Wb(wi), bias, res, Cf, Cb, 2048, N, K);
    }
  };

  auto Gdown = [&](const bf16* A, int wi, int bi, const float* res,
                   const bf16* bms, float* Cf, bf16* Cb, int K){
    gemm_chunk64<<<dim3(8, 32, 2), 256, 0, stream>>>(A, Wb(wi), hid, 512, K, K/2);
    down_epi_kernel<<<4096, 256, 0, stream>>>(hid, 2, Wb(bi), res, srcf, bms, Cf, Cb);
  };

  pe_kernel<<<(POS_N*32+255)/256, 256, 0, stream>>>(Wb(1), Wb(11), pe, lsum);
  G(srcb, 9, 10, nullptr, xattn, xattnb, 544, 512, 0);
  newkey_kernel<<<128, 256, 0, stream>>>(xattn, out_key);
  attn_exp_mfma<<<dim3(34,32,8), 256, 0, stream>>>(xattnb, xattn, Wb(2), pe, lsum, attnw);
  // ff1
  G(srcb, 12, 13, nullptr, nullptr, hidb, 1536, 512, 1);
  Gdown(hidb, 14, 15, srcf, nullptr, cur, curb, 1536);
  // nonlin attention
  G(curb, 24, 25, nullptr, hid, nullptr, 1152, 512, 0);
  na_mid_kernel<<<dim3(68,12), 256, 0, stream>>>(hid, Wb(3), xcT, out_nl);
  gemm_chunk64<<<dim3(6,32,2), 256, 0, stream>>>(attnw, xcT, napart, ATT_N, KV_LEN, 1088);
  na_epi_kernel<<<(S_LEN*ATT_N+255)/256, 256, 0, stream>>>(napart, hid, lsum, t1b);
  G(t1b, 26, 27, cur, cur, curb, 512, 384, 0);
  // self-attn 1
  G(curb, 28, 29, nullptr, v96, nullptr, 96, 512, 0);
  vc_build_kernel<<<(KV_LEN*96+255)/256, 256, 0, stream>>>(v96, Wb(4), vcT, out_v1);
  apply_gemm<<<dim3(32,8), 256, 0, stream>>>(attnw, vcT, lsum, t1b);
  G(t1b, 30, 31, cur, cur, curb, 512, 96, 0);
  // conv 1
  G(curb, 36, 37, nullptr, hid, nullptr, 1024, 512, 0);
  conv_glu_kernel<<<dim3(64,16), 256, 0, stream>>>(hid, uT, out_c1);
  dwconv_kernel<<<dim3(32,16), 256, 0, stream>>>(uT, Wb(6), Wb(38), Wb(39), t1b);
  G(t1b, 40, 41, cur, cur, curb, 512, 512, 0);
  // ff2 (mid-bypass fused into epilogue)
  G(curb, 16, 17, nullptr, nullptr, hidb, 2048, 512, 1);
  Gdown(hidb, 18, 19, cur, Wb(50), cur, curb, 2048);
  // self-attn 2
  G(curb, 32, 33, nullptr, v96, nullptr, 96, 512, 0);
  vc_build_kernel<<<(KV_LEN*96+255)/256, 256, 0, stream>>>(v96, Wb(5), vcT, out_v2);
  apply_gemm<<<dim3(32,8), 256, 0, stream>>>(attnw, vcT, lsum, t1b);
  G(t1b, 34, 35, cur, cur, curb, 512, 96, 0);
  // conv 2
  G(curb, 42, 43, nullptr, hid, nullptr, 1024, 512, 0);
  conv_glu_kernel<<<dim3(64,16), 256, 0, stream>>>(hid, uT, out_c2);
  dwconv_kernel<<<dim3(32,16), 256, 0, stream>>>(uT, Wb(7), Wb(44), Wb(45), t1b);
  G(t1b, 46, 47, cur, cur, curb, 512, 512, 0);
  // ff3
  G(curb, 20, 21, nullptr, nullptr, hidb, 2560, 512, 1);
  Gdown(hidb, 22, 23, cur, nullptr, cur, curb, 2560);
  final_kernel<<<2048, 256, 0, stream>>>(cur, srcf, Wb(48), Wb(49), Wb(51), out0);
}